// Round 2
// baseline (608.719 us; speedup 1.0000x reference)
//
#include <hip/hip_runtime.h>

#define N_NODES 20000
#define N_EDGES 640000
#define F 128
#define CAP 128   // max in-degree bucket capacity; Poisson(32) => P(deg>=128) ~ 1e-37

// ---------------------------------------------------------------------------
// Single-pass bucket build: bucket[d*CAP + k] = k-th src with dst==d.
// Replaces count+scan+fill (the serial scan was ~1/3 of round-1 runtime).
// ---------------------------------------------------------------------------
__global__ void bucket_kernel(const int* __restrict__ src, const int* __restrict__ dst,
                              int* __restrict__ cnt, int* __restrict__ bucket) {
    int e = blockIdx.x * blockDim.x + threadIdx.x;
    if (e >= N_EDGES) return;
    int d = dst[e];
    int pos = atomicAdd(&cnt[d], 1);
    if (pos < CAP) bucket[(size_t)d * CAP + pos] = src[e];
}

// ---------------------------------------------------------------------------
// Mean aggregation: one wave per node, lane owns 2 features (float2).
// Indices read wave-uniform via int4 (broadcast); gather unrolled x8 so
// 8 independent global loads are in flight per wave (round-1 version had
// exactly 1 -> latency bound at 50us).
// ---------------------------------------------------------------------------
__global__ void agg_mean_kernel(const float* __restrict__ feat, const int* __restrict__ cnt,
                                const int* __restrict__ bucket, float* __restrict__ out) {
    int wid  = (blockIdx.x * blockDim.x + threadIdx.x) >> 6;
    int lane = threadIdx.x & 63;
    if (wid >= N_NODES) return;
    int deg = cnt[wid];
    const int* lst = bucket + (size_t)wid * CAP;
    const float2* f2 = (const float2*)feat;
    float ax = 0.f, ay = 0.f;
    int j = 0;
    for (; j + 8 <= deg; j += 8) {
        int4 i0 = *(const int4*)(lst + j);
        int4 i1 = *(const int4*)(lst + j + 4);
        float2 v0 = f2[(size_t)i0.x * 64 + lane];
        float2 v1 = f2[(size_t)i0.y * 64 + lane];
        float2 v2 = f2[(size_t)i0.z * 64 + lane];
        float2 v3 = f2[(size_t)i0.w * 64 + lane];
        float2 v4 = f2[(size_t)i1.x * 64 + lane];
        float2 v5 = f2[(size_t)i1.y * 64 + lane];
        float2 v6 = f2[(size_t)i1.z * 64 + lane];
        float2 v7 = f2[(size_t)i1.w * 64 + lane];
        ax += (v0.x + v1.x) + (v2.x + v3.x) + ((v4.x + v5.x) + (v6.x + v7.x));
        ay += (v0.y + v1.y) + (v2.y + v3.y) + ((v4.y + v5.y) + (v6.y + v7.y));
    }
    for (; j < deg; ++j) {
        float2 v = f2[(size_t)lst[j] * 64 + lane];
        ax += v.x; ay += v.y;
    }
    float sc = 1.0f / fmaxf((float)deg, 1.0f);
    float2 o; o.x = ax * sc; o.y = ay * sc;
    ((float2*)out)[(size_t)wid * 64 + lane] = o;
}

// ---------------------------------------------------------------------------
// C[Mx128] = relu(A[Mx128] @ W[128x128] + b). 256 thr: 32 rows x 128 cols,
// 4x4 micro-tile/thread. A staged in LDS, row stride 132 (16B-aligned float4
// reads, 4-bank skew). K-loop unrolled x4.
// ---------------------------------------------------------------------------
__global__ void gemm_bias_relu_kernel(const float* __restrict__ A, const float* __restrict__ W,
                                      const float* __restrict__ b, float* __restrict__ C) {
    __shared__ float As[32][F + 4];
    int tid  = threadIdx.x;
    int row0 = blockIdx.x * 32;

    const float4* A4 = (const float4*)(A + (size_t)row0 * F);
    for (int i = tid; i < 32 * 32; i += 256) {
        float4 v = A4[i];
        int r = i >> 5, c4 = (i & 31) * 4;
        *(float4*)&As[r][c4] = v;
    }
    __syncthreads();

    int tx = tid & 31, ty = tid >> 5;
    int c0 = tx * 4, r0 = ty * 4;
    float acc[4][4] = {};

    for (int k = 0; k < F; k += 4) {
        float4 a4[4];
#pragma unroll
        for (int i = 0; i < 4; ++i) a4[i] = *(const float4*)&As[r0 + i][k];
#pragma unroll
        for (int u = 0; u < 4; ++u) {
            float4 w = *(const float4*)(W + (size_t)(k + u) * F + c0);
#pragma unroll
            for (int i = 0; i < 4; ++i) {
                float a = (u == 0) ? a4[i].x : (u == 1) ? a4[i].y : (u == 2) ? a4[i].z : a4[i].w;
                acc[i][0] += a * w.x;
                acc[i][1] += a * w.y;
                acc[i][2] += a * w.z;
                acc[i][3] += a * w.w;
            }
        }
    }

    float4 bias = *(const float4*)(b + c0);
#pragma unroll
    for (int i = 0; i < 4; ++i) {
        float4 o;
        o.x = fmaxf(acc[i][0] + bias.x, 0.f);
        o.y = fmaxf(acc[i][1] + bias.y, 0.f);
        o.z = fmaxf(acc[i][2] + bias.z, 0.f);
        o.w = fmaxf(acc[i][3] + bias.w, 0.f);
        *(float4*)(C + (size_t)(row0 + r0 + i) * F + c0) = o;
    }
}

// ---------------------------------------------------------------------------
// Layer-2 GEMM with the 128->2 output projection fused into the epilogue:
// h = relu(A @ W2 + b2);  out = h @ W3 + b3  (no h materialization).
// Row-sum over the 32 col-group lanes via width-32 shfl reduce.
// ---------------------------------------------------------------------------
__global__ void gemm2_final_kernel(const float* __restrict__ A, const float* __restrict__ W,
                                   const float* __restrict__ b, const float* __restrict__ W3,
                                   const float* __restrict__ b3, float* __restrict__ out) {
    __shared__ float As[32][F + 4];
    int tid  = threadIdx.x;
    int row0 = blockIdx.x * 32;

    const float4* A4 = (const float4*)(A + (size_t)row0 * F);
    for (int i = tid; i < 32 * 32; i += 256) {
        float4 v = A4[i];
        int r = i >> 5, c4 = (i & 31) * 4;
        *(float4*)&As[r][c4] = v;
    }
    __syncthreads();

    int tx = tid & 31, ty = tid >> 5;
    int c0 = tx * 4, r0 = ty * 4;
    float acc[4][4] = {};

    for (int k = 0; k < F; k += 4) {
        float4 a4[4];
#pragma unroll
        for (int i = 0; i < 4; ++i) a4[i] = *(const float4*)&As[r0 + i][k];
#pragma unroll
        for (int u = 0; u < 4; ++u) {
            float4 w = *(const float4*)(W + (size_t)(k + u) * F + c0);
#pragma unroll
            for (int i = 0; i < 4; ++i) {
                float a = (u == 0) ? a4[i].x : (u == 1) ? a4[i].y : (u == 2) ? a4[i].z : a4[i].w;
                acc[i][0] += a * w.x;
                acc[i][1] += a * w.y;
                acc[i][2] += a * w.z;
                acc[i][3] += a * w.w;
            }
        }
    }

    float4 bias = *(const float4*)(b + c0);
    // W3 is [128][2] row-major; this thread needs rows c0..c0+3.
    float2 w3[4];
#pragma unroll
    for (int j = 0; j < 4; ++j) w3[j] = ((const float2*)W3)[c0 + j];
    float2 b3v = *(const float2*)b3;

#pragma unroll
    for (int i = 0; i < 4; ++i) {
        float v0 = fmaxf(acc[i][0] + bias.x, 0.f);
        float v1 = fmaxf(acc[i][1] + bias.y, 0.f);
        float v2 = fmaxf(acc[i][2] + bias.z, 0.f);
        float v3 = fmaxf(acc[i][3] + bias.w, 0.f);
        float p0 = v0 * w3[0].x + v1 * w3[1].x + v2 * w3[2].x + v3 * w3[3].x;
        float p1 = v0 * w3[0].y + v1 * w3[1].y + v2 * w3[2].y + v3 * w3[3].y;
#pragma unroll
        for (int off = 16; off > 0; off >>= 1) {
            p0 += __shfl_down(p0, off, 32);
            p1 += __shfl_down(p1, off, 32);
        }
        if (tx == 0) {
            float2 o; o.x = p0 + b3v.x; o.y = p1 + b3v.y;
            *(float2*)(out + (size_t)(row0 + r0 + i) * 2) = o;
        }
    }
}

// ---------------------------------------------------------------------------
extern "C" void kernel_launch(void* const* d_in, const int* in_sizes, int n_in,
                              void* d_out, int out_size, void* d_ws, size_t ws_size,
                              hipStream_t stream) {
    const float* x   = (const float*)d_in[0];
    const int*   ei  = (const int*)d_in[1];
    const int*   src = ei;
    const int*   dst = ei + N_EDGES;
    const float* W1 = (const float*)d_in[2];
    const float* b1 = (const float*)d_in[3];
    const float* W2 = (const float*)d_in[4];
    const float* b2 = (const float*)d_in[5];
    const float* W3 = (const float*)d_in[6];
    const float* b3 = (const float*)d_in[7];
    float* out = (float*)d_out;

    char* base = (char*)d_ws;
    size_t off = 0;
    auto take = [&](size_t bytes) -> char* {
        char* p = base + off;
        off += (bytes + 255) & ~(size_t)255;
        return p;
    };
    int*   cnt    = (int*)  take(N_NODES * sizeof(int));
    int*   bucket = (int*)  take((size_t)N_NODES * CAP * sizeof(int));
    float* aggr   = (float*)take((size_t)N_NODES * F * sizeof(float));
    float* h      = (float*)take((size_t)N_NODES * F * sizeof(float));

    hipMemsetAsync(cnt, 0, N_NODES * sizeof(int), stream);
    bucket_kernel<<<(N_EDGES + 255) / 256, 256, 0, stream>>>(src, dst, cnt, bucket);

    // layer 1: aggr = mean(x); h = relu(aggr @ W1 + b1)
    agg_mean_kernel<<<(N_NODES * 64 + 255) / 256, 256, 0, stream>>>(x, cnt, bucket, aggr);
    gemm_bias_relu_kernel<<<N_NODES / 32, 256, 0, stream>>>(aggr, W1, b1, h);
    // layer 2 + fused output projection
    agg_mean_kernel<<<(N_NODES * 64 + 255) / 256, 256, 0, stream>>>(h, cnt, bucket, aggr);
    gemm2_final_kernel<<<N_NODES / 32, 256, 0, stream>>>(aggr, W2, b2, W3, b3, out);
}

// Round 3
// 447.448 us; speedup vs baseline: 1.3604x; 1.3604x over previous
//
#include <hip/hip_runtime.h>

#define N_NODES 20000
#define N_EDGES 640000
#define F 128
#define CAP 128   // max in-degree bucket; deg ~ Binomial(640K, 1/20K), P(deg>=128) ~ 1e-37

// NOTE: __launch_bounds__(256) on EVERY kernel. HIP's default assumes 1024
// threads/block -> 64-VGPR cap -> round-2's gemm2_final spilled acc[] to
// scratch (518 MB fetch + 501 MB write of pure spill traffic, 416 us).

// ---------------------------------------------------------------------------
// Single-pass bucket build: bucket[d*CAP + k] = k-th src with dst==d.
// ---------------------------------------------------------------------------
__global__ __launch_bounds__(256)
void bucket_kernel(const int* __restrict__ src, const int* __restrict__ dst,
                   int* __restrict__ cnt, int* __restrict__ bucket) {
    int e = blockIdx.x * blockDim.x + threadIdx.x;
    if (e >= N_EDGES) return;
    int d = dst[e];
    int pos = atomicAdd(&cnt[d], 1);
    if (pos < CAP) bucket[(size_t)d * CAP + pos] = src[e];
}

// ---------------------------------------------------------------------------
// Mean aggregation: one wave per node, lane owns 2 features (float2).
// Wave-uniform int4 index loads; gather unrolled x8 -> 8 loads in flight.
// ---------------------------------------------------------------------------
__global__ __launch_bounds__(256)
void agg_mean_kernel(const float* __restrict__ feat, const int* __restrict__ cnt,
                     const int* __restrict__ bucket, float* __restrict__ out) {
    int wid  = (blockIdx.x * blockDim.x + threadIdx.x) >> 6;
    int lane = threadIdx.x & 63;
    if (wid >= N_NODES) return;
    int deg = cnt[wid];
    const int* lst = bucket + (size_t)wid * CAP;
    const float2* f2 = (const float2*)feat;
    float ax = 0.f, ay = 0.f;
    int j = 0;
    for (; j + 8 <= deg; j += 8) {
        int4 i0 = *(const int4*)(lst + j);
        int4 i1 = *(const int4*)(lst + j + 4);
        float2 v0 = f2[(size_t)i0.x * 64 + lane];
        float2 v1 = f2[(size_t)i0.y * 64 + lane];
        float2 v2 = f2[(size_t)i0.z * 64 + lane];
        float2 v3 = f2[(size_t)i0.w * 64 + lane];
        float2 v4 = f2[(size_t)i1.x * 64 + lane];
        float2 v5 = f2[(size_t)i1.y * 64 + lane];
        float2 v6 = f2[(size_t)i1.z * 64 + lane];
        float2 v7 = f2[(size_t)i1.w * 64 + lane];
        ax += (v0.x + v1.x) + (v2.x + v3.x) + ((v4.x + v5.x) + (v6.x + v7.x));
        ay += (v0.y + v1.y) + (v2.y + v3.y) + ((v4.y + v5.y) + (v6.y + v7.y));
    }
    for (; j < deg; ++j) {
        float2 v = f2[(size_t)lst[j] * 64 + lane];
        ax += v.x; ay += v.y;
    }
    float sc = 1.0f / fmaxf((float)deg, 1.0f);
    float2 o; o.x = ax * sc; o.y = ay * sc;
    ((float2*)out)[(size_t)wid * 64 + lane] = o;
}

// ---------------------------------------------------------------------------
// C[Mx128] = relu(A[Mx128] @ W[128x128] + b). 256 thr: 32 rows x 128 cols,
// 4x4 micro-tile/thread. A in LDS (stride 132), K-loop unrolled x4.
// ---------------------------------------------------------------------------
__global__ __launch_bounds__(256)
void gemm_bias_relu_kernel(const float* __restrict__ A, const float* __restrict__ W,
                           const float* __restrict__ b, float* __restrict__ C) {
    __shared__ float As[32][F + 4];
    int tid  = threadIdx.x;
    int row0 = blockIdx.x * 32;

    const float4* A4 = (const float4*)(A + (size_t)row0 * F);
    for (int i = tid; i < 32 * 32; i += 256) {
        float4 v = A4[i];
        int r = i >> 5, c4 = (i & 31) * 4;
        *(float4*)&As[r][c4] = v;
    }
    __syncthreads();

    int tx = tid & 31, ty = tid >> 5;
    int c0 = tx * 4, r0 = ty * 4;
    float acc[4][4] = {};

    for (int k = 0; k < F; k += 4) {
        float4 a4[4];
#pragma unroll
        for (int i = 0; i < 4; ++i) a4[i] = *(const float4*)&As[r0 + i][k];
#pragma unroll
        for (int u = 0; u < 4; ++u) {
            float4 w = *(const float4*)(W + (size_t)(k + u) * F + c0);
#pragma unroll
            for (int i = 0; i < 4; ++i) {
                float a = (u == 0) ? a4[i].x : (u == 1) ? a4[i].y : (u == 2) ? a4[i].z : a4[i].w;
                acc[i][0] += a * w.x;
                acc[i][1] += a * w.y;
                acc[i][2] += a * w.z;
                acc[i][3] += a * w.w;
            }
        }
    }

    float4 bias = *(const float4*)(b + c0);
#pragma unroll
    for (int i = 0; i < 4; ++i) {
        float4 o;
        o.x = fmaxf(acc[i][0] + bias.x, 0.f);
        o.y = fmaxf(acc[i][1] + bias.y, 0.f);
        o.z = fmaxf(acc[i][2] + bias.z, 0.f);
        o.w = fmaxf(acc[i][3] + bias.w, 0.f);
        *(float4*)(C + (size_t)(row0 + r0 + i) * F + c0) = o;
    }
}

// ---------------------------------------------------------------------------
// Layer-2 GEMM with fused 128->2 output projection:
// h = relu(A @ W2 + b2);  out = h @ W3 + b3  (h never materialized).
// ---------------------------------------------------------------------------
__global__ __launch_bounds__(256)
void gemm2_final_kernel(const float* __restrict__ A, const float* __restrict__ W,
                        const float* __restrict__ b, const float* __restrict__ W3,
                        const float* __restrict__ b3, float* __restrict__ out) {
    __shared__ float As[32][F + 4];
    int tid  = threadIdx.x;
    int row0 = blockIdx.x * 32;

    const float4* A4 = (const float4*)(A + (size_t)row0 * F);
    for (int i = tid; i < 32 * 32; i += 256) {
        float4 v = A4[i];
        int r = i >> 5, c4 = (i & 31) * 4;
        *(float4*)&As[r][c4] = v;
    }
    __syncthreads();

    int tx = tid & 31, ty = tid >> 5;
    int c0 = tx * 4, r0 = ty * 4;
    float acc[4][4] = {};

    for (int k = 0; k < F; k += 4) {
        float4 a4[4];
#pragma unroll
        for (int i = 0; i < 4; ++i) a4[i] = *(const float4*)&As[r0 + i][k];
#pragma unroll
        for (int u = 0; u < 4; ++u) {
            float4 w = *(const float4*)(W + (size_t)(k + u) * F + c0);
#pragma unroll
            for (int i = 0; i < 4; ++i) {
                float a = (u == 0) ? a4[i].x : (u == 1) ? a4[i].y : (u == 2) ? a4[i].z : a4[i].w;
                acc[i][0] += a * w.x;
                acc[i][1] += a * w.y;
                acc[i][2] += a * w.z;
                acc[i][3] += a * w.w;
            }
        }
    }

    float4 bias = *(const float4*)(b + c0);
    float2 w3[4];
#pragma unroll
    for (int j = 0; j < 4; ++j) w3[j] = ((const float2*)W3)[c0 + j];
    float2 b3v = *(const float2*)b3;

#pragma unroll
    for (int i = 0; i < 4; ++i) {
        float v0 = fmaxf(acc[i][0] + bias.x, 0.f);
        float v1 = fmaxf(acc[i][1] + bias.y, 0.f);
        float v2 = fmaxf(acc[i][2] + bias.z, 0.f);
        float v3 = fmaxf(acc[i][3] + bias.w, 0.f);
        float p0 = v0 * w3[0].x + v1 * w3[1].x + v2 * w3[2].x + v3 * w3[3].x;
        float p1 = v0 * w3[0].y + v1 * w3[1].y + v2 * w3[2].y + v3 * w3[3].y;
#pragma unroll
        for (int off = 16; off > 0; off >>= 1) {
            p0 += __shfl_down(p0, off, 32);
            p1 += __shfl_down(p1, off, 32);
        }
        if (tx == 0) {
            float2 o; o.x = p0 + b3v.x; o.y = p1 + b3v.y;
            *(float2*)(out + (size_t)(row0 + r0 + i) * 2) = o;
        }
    }
}

// ---------------------------------------------------------------------------
extern "C" void kernel_launch(void* const* d_in, const int* in_sizes, int n_in,
                              void* d_out, int out_size, void* d_ws, size_t ws_size,
                              hipStream_t stream) {
    const float* x   = (const float*)d_in[0];
    const int*   ei  = (const int*)d_in[1];
    const int*   src = ei;
    const int*   dst = ei + N_EDGES;
    const float* W1 = (const float*)d_in[2];
    const float* b1 = (const float*)d_in[3];
    const float* W2 = (const float*)d_in[4];
    const float* b2 = (const float*)d_in[5];
    const float* W3 = (const float*)d_in[6];
    const float* b3 = (const float*)d_in[7];
    float* out = (float*)d_out;

    char* base = (char*)d_ws;
    size_t off = 0;
    auto take = [&](size_t bytes) -> char* {
        char* p = base + off;
        off += (bytes + 255) & ~(size_t)255;
        return p;
    };
    int*   cnt    = (int*)  take(N_NODES * sizeof(int));
    int*   bucket = (int*)  take((size_t)N_NODES * CAP * sizeof(int));
    float* aggr   = (float*)take((size_t)N_NODES * F * sizeof(float));
    float* h      = (float*)take((size_t)N_NODES * F * sizeof(float));

    hipMemsetAsync(cnt, 0, N_NODES * sizeof(int), stream);
    bucket_kernel<<<(N_EDGES + 255) / 256, 256, 0, stream>>>(src, dst, cnt, bucket);

    // layer 1
    agg_mean_kernel<<<(N_NODES * 64 + 255) / 256, 256, 0, stream>>>(x, cnt, bucket, aggr);
    gemm_bias_relu_kernel<<<N_NODES / 32, 256, 0, stream>>>(aggr, W1, b1, h);
    // layer 2 + fused output projection
    agg_mean_kernel<<<(N_NODES * 64 + 255) / 256, 256, 0, stream>>>(h, cnt, bucket, aggr);
    gemm2_final_kernel<<<N_NODES / 32, 256, 0, stream>>>(aggr, W2, b2, W3, b3, out);
}

// Round 4
// 218.236 us; speedup vs baseline: 2.7893x; 2.0503x over previous
//
#include <hip/hip_runtime.h>

#define N_NODES 20000
#define N_EDGES 640000
#define F 128
#define CAP 128   // max in-degree bucket; deg ~ Binomial(640K, 1/20K), P(deg>=128) ~ 1e-37

// HISTORY:
//  - r2: fused gemm2+projection spilled (64-VGPR cap): 1.04 GB scratch traffic.
//  - r3: __launch_bounds__(256) halved it but the fused epilogue STILL forced
//    VGPR=256 + 565 MB spill (compiler hoists all W loads once acc is consumed
//    non-uniformly in the epilogue). Fix: DE-FUSE. gemm_bias_relu is proven
//    44-VGPR / no-spill; final 128->2 projection is its own tiny kernel.

// ---------------------------------------------------------------------------
// Single-pass bucket build: bucket[d*CAP + k] = k-th src with dst==d.
// ---------------------------------------------------------------------------
__global__ __launch_bounds__(256)
void bucket_kernel(const int* __restrict__ src, const int* __restrict__ dst,
                   int* __restrict__ cnt, int* __restrict__ bucket) {
    int e = blockIdx.x * blockDim.x + threadIdx.x;
    if (e >= N_EDGES) return;
    int d = dst[e];
    int pos = atomicAdd(&cnt[d], 1);
    if (pos < CAP) bucket[(size_t)d * CAP + pos] = src[e];
}

// ---------------------------------------------------------------------------
// Mean aggregation: one wave per node, lane owns 2 features (float2).
// Wave-uniform int4 index loads; gather unrolled x8 -> 8 loads in flight.
// ---------------------------------------------------------------------------
__global__ __launch_bounds__(256)
void agg_mean_kernel(const float* __restrict__ feat, const int* __restrict__ cnt,
                     const int* __restrict__ bucket, float* __restrict__ out) {
    int wid  = (blockIdx.x * blockDim.x + threadIdx.x) >> 6;
    int lane = threadIdx.x & 63;
    if (wid >= N_NODES) return;
    int deg = cnt[wid];
    const int* lst = bucket + (size_t)wid * CAP;
    const float2* f2 = (const float2*)feat;
    float ax = 0.f, ay = 0.f;
    int j = 0;
    for (; j + 8 <= deg; j += 8) {
        int4 i0 = *(const int4*)(lst + j);
        int4 i1 = *(const int4*)(lst + j + 4);
        float2 v0 = f2[(size_t)i0.x * 64 + lane];
        float2 v1 = f2[(size_t)i0.y * 64 + lane];
        float2 v2 = f2[(size_t)i0.z * 64 + lane];
        float2 v3 = f2[(size_t)i0.w * 64 + lane];
        float2 v4 = f2[(size_t)i1.x * 64 + lane];
        float2 v5 = f2[(size_t)i1.y * 64 + lane];
        float2 v6 = f2[(size_t)i1.z * 64 + lane];
        float2 v7 = f2[(size_t)i1.w * 64 + lane];
        ax += (v0.x + v1.x) + (v2.x + v3.x) + ((v4.x + v5.x) + (v6.x + v7.x));
        ay += (v0.y + v1.y) + (v2.y + v3.y) + ((v4.y + v5.y) + (v6.y + v7.y));
    }
    for (; j < deg; ++j) {
        float2 v = f2[(size_t)lst[j] * 64 + lane];
        ax += v.x; ay += v.y;
    }
    float sc = 1.0f / fmaxf((float)deg, 1.0f);
    float2 o; o.x = ax * sc; o.y = ay * sc;
    ((float2*)out)[(size_t)wid * 64 + lane] = o;
}

// ---------------------------------------------------------------------------
// C[Mx128] = relu(A[Mx128] @ W[128x128] + b). 256 thr: 32 rows x 128 cols,
// 4x4 micro-tile/thread. A in LDS (stride 132), K-loop unrolled x4.
// Proven 44-VGPR, no spill. Safe to run in-place (C == A): each block reads
// its 32 A-rows into LDS before __syncthreads and writes only those rows.
// ---------------------------------------------------------------------------
__global__ __launch_bounds__(256)
void gemm_bias_relu_kernel(const float* __restrict__ A, const float* __restrict__ W,
                           const float* __restrict__ b, float* __restrict__ C) {
    __shared__ float As[32][F + 4];
    int tid  = threadIdx.x;
    int row0 = blockIdx.x * 32;

    const float4* A4 = (const float4*)(A + (size_t)row0 * F);
    for (int i = tid; i < 32 * 32; i += 256) {
        float4 v = A4[i];
        int r = i >> 5, c4 = (i & 31) * 4;
        *(float4*)&As[r][c4] = v;
    }
    __syncthreads();

    int tx = tid & 31, ty = tid >> 5;
    int c0 = tx * 4, r0 = ty * 4;
    float acc[4][4] = {};

    for (int k = 0; k < F; k += 4) {
        float4 a4[4];
#pragma unroll
        for (int i = 0; i < 4; ++i) a4[i] = *(const float4*)&As[r0 + i][k];
#pragma unroll
        for (int u = 0; u < 4; ++u) {
            float4 w = *(const float4*)(W + (size_t)(k + u) * F + c0);
#pragma unroll
            for (int i = 0; i < 4; ++i) {
                float a = (u == 0) ? a4[i].x : (u == 1) ? a4[i].y : (u == 2) ? a4[i].z : a4[i].w;
                acc[i][0] += a * w.x;
                acc[i][1] += a * w.y;
                acc[i][2] += a * w.z;
                acc[i][3] += a * w.w;
            }
        }
    }

    float4 bias = *(const float4*)(b + c0);
#pragma unroll
    for (int i = 0; i < 4; ++i) {
        float4 o;
        o.x = fmaxf(acc[i][0] + bias.x, 0.f);
        o.y = fmaxf(acc[i][1] + bias.y, 0.f);
        o.z = fmaxf(acc[i][2] + bias.z, 0.f);
        o.w = fmaxf(acc[i][3] + bias.w, 0.f);
        *(float4*)(C + (size_t)(row0 + r0 + i) * F + c0) = o;
    }
}

// ---------------------------------------------------------------------------
// out[N x 2] = h[N x 128] @ W3[128 x 2] + b3. One wave per node, shuffle
// reduce. No relu.
// ---------------------------------------------------------------------------
__global__ __launch_bounds__(256)
void final_kernel(const float* __restrict__ h, const float* __restrict__ W3,
                  const float* __restrict__ b3, float* __restrict__ out) {
    int wid  = (blockIdx.x * blockDim.x + threadIdx.x) >> 6;
    int lane = threadIdx.x & 63;
    if (wid >= N_NODES) return;
    float2 v = ((const float2*)h)[(size_t)wid * 64 + lane];   // h[., 2l], h[., 2l+1]
    float4 w = ((const float4*)W3)[lane];                     // W3[2l][0..1], W3[2l+1][0..1]
    float a0 = v.x * w.x + v.y * w.z;
    float a1 = v.x * w.y + v.y * w.w;
#pragma unroll
    for (int off = 32; off > 0; off >>= 1) {
        a0 += __shfl_down(a0, off);
        a1 += __shfl_down(a1, off);
    }
    if (lane == 0) {
        out[(size_t)wid * 2]     = a0 + b3[0];
        out[(size_t)wid * 2 + 1] = a1 + b3[1];
    }
}

// ---------------------------------------------------------------------------
extern "C" void kernel_launch(void* const* d_in, const int* in_sizes, int n_in,
                              void* d_out, int out_size, void* d_ws, size_t ws_size,
                              hipStream_t stream) {
    const float* x   = (const float*)d_in[0];
    const int*   ei  = (const int*)d_in[1];
    const int*   src = ei;
    const int*   dst = ei + N_EDGES;
    const float* W1 = (const float*)d_in[2];
    const float* b1 = (const float*)d_in[3];
    const float* W2 = (const float*)d_in[4];
    const float* b2 = (const float*)d_in[5];
    const float* W3 = (const float*)d_in[6];
    const float* b3 = (const float*)d_in[7];
    float* out = (float*)d_out;

    char* base = (char*)d_ws;
    size_t off = 0;
    auto take = [&](size_t bytes) -> char* {
        char* p = base + off;
        off += (bytes + 255) & ~(size_t)255;
        return p;
    };
    int*   cnt    = (int*)  take(N_NODES * sizeof(int));
    int*   bucket = (int*)  take((size_t)N_NODES * CAP * sizeof(int));
    float* aggr   = (float*)take((size_t)N_NODES * F * sizeof(float));
    float* h      = (float*)take((size_t)N_NODES * F * sizeof(float));

    hipMemsetAsync(cnt, 0, N_NODES * sizeof(int), stream);
    bucket_kernel<<<(N_EDGES + 255) / 256, 256, 0, stream>>>(src, dst, cnt, bucket);

    // layer 1: aggr = mean(x); h = relu(aggr @ W1 + b1)
    agg_mean_kernel<<<(N_NODES * 64 + 255) / 256, 256, 0, stream>>>(x, cnt, bucket, aggr);
    gemm_bias_relu_kernel<<<N_NODES / 32, 256, 0, stream>>>(aggr, W1, b1, h);
    // layer 2: aggr = mean(h); aggr = relu(aggr @ W2 + b2)  (in-place)
    agg_mean_kernel<<<(N_NODES * 64 + 255) / 256, 256, 0, stream>>>(h, cnt, bucket, aggr);
    gemm_bias_relu_kernel<<<N_NODES / 32, 256, 0, stream>>>(aggr, W2, b2, aggr);
    // output projection
    final_kernel<<<(N_NODES * 64 + 255) / 256, 256, 0, stream>>>(aggr, W3, b3, out);
}